// Round 1
// baseline (3101.773 us; speedup 1.0000x reference)
//
#include <hip/hip_runtime.h>
#include <cmath>

#define HID 51
#define NG  204      // 4*HID gates per cell
#define BATCH 256
#define BLK 768      // 3 layer-groups x 256 threads (12 waves)

// One block per batch element. Thread (layer = tid>>8, g = tid&255, g<204)
// holds the weight rows for gate g of layer `layer` in registers.
// Layers are time-skewed: at tick tau, layer l processes timestep t = tau - l.
// Phase A: all gates computed in parallel into LDS. Phase B: per-unit cell
// update (c in register of unit thread), h -> LDS. Output (h of layer index 2
// dot Wl) runs 3 ticks behind on spare threads.
__global__ __launch_bounds__(BLK, 3)
void lstm3_kernel(const float* __restrict__ x,
                  const float* __restrict__ Wih1, const float* __restrict__ Whh1,
                  const float* __restrict__ bih1, const float* __restrict__ bhh1,
                  const float* __restrict__ Wih,  const float* __restrict__ Whh,
                  const float* __restrict__ bih,  const float* __restrict__ bhh,
                  const float* __restrict__ Wl,   const float* __restrict__ bl,
                  float* __restrict__ out, int T)
{
    const int b     = blockIdx.x;
    const int tid   = threadIdx.x;
    const int layer = tid >> 8;     // 0,1,2  (wave-uniform)
    const int g     = tid & 255;
    const bool gate_thread = (g < NG);

    __shared__ __align__(16) float xbuf[2048];
    __shared__ __align__(16) float hbuf[3][52];   // padded row (hbuf[l][51] == 0)
    __shared__ __align__(16) float gbuf[3][NG];
    __shared__ float opart[4];

    // stage x row (read-once) into LDS
    for (int i = tid; i < T; i += BLK) xbuf[i] = x[b * T + i];
    // zero h state (+pad)
    if (tid < 3 * 52) ((float*)hbuf)[tid] = 0.0f;

    // ---- load weights into registers ----
    float wA[52];   // layer0: Whh1 row ; layers 1,2: Wih row
    float wB[52];   // layers 1,2: Whh row
    float wx = 0.f, bias = 0.f;
    if (gate_thread) {
        if (layer == 0) {
            wx   = Wih1[g];
            bias = bih1[g] + bhh1[g];
            #pragma unroll
            for (int j = 0; j < 51; ++j) wA[j] = Whh1[g * 51 + j];
            wA[51] = 0.f;
            #pragma unroll
            for (int j = 0; j < 52; ++j) wB[j] = 0.f;
        } else {
            const int l = layer - 1;               // stacked-weight index 0 or 1
            const float* wih_row = Wih + (size_t)(l * NG + g) * 51;
            const float* whh_row = Whh + (size_t)(l * NG + g) * 51;
            bias = bih[l * NG + g] + bhh[l * NG + g];
            #pragma unroll
            for (int j = 0; j < 51; ++j) { wA[j] = wih_row[j]; wB[j] = whh_row[j]; }
            wA[51] = 0.f; wB[51] = 0.f;
        }
    }
    // output weights on layer-0 spares g=204..207 (13 each)
    float wl[13];
    if (layer == 0 && g >= 204 && g < 208) {
        const int k = g - 204;
        #pragma unroll
        for (int j = 0; j < 13; ++j) {
            const int idx = k * 13 + j;
            wl[j] = (idx < 51) ? Wl[idx] : 0.f;
        }
    }
    float blv = 0.f;
    if (layer == 0 && g == 208) blv = bl[0];

    float c_state = 0.f;
    __syncthreads();

    const int TICKS = T + 3;
    for (int tau = 0; tau < TICKS; ++tau) {
        // ---------------- phase A: gate matvecs ----------------
        if (gate_thread) {
            const int t = tau - layer;
            if (t >= 0 && t < T) {
                float acc = bias;
                if (layer == 0) {
                    acc += wx * xbuf[t];
                    const float4* hp = (const float4*)hbuf[0];
                    #pragma unroll
                    for (int j4 = 0; j4 < 13; ++j4) {
                        const float4 h4 = hp[j4];
                        acc += wA[j4*4+0]*h4.x + wA[j4*4+1]*h4.y
                             + wA[j4*4+2]*h4.z + wA[j4*4+3]*h4.w;
                    }
                } else {
                    const float4* hpA = (const float4*)hbuf[layer - 1];
                    const float4* hpB = (const float4*)hbuf[layer];
                    #pragma unroll
                    for (int j4 = 0; j4 < 13; ++j4) {
                        const float4 a4 = hpA[j4];
                        acc += wA[j4*4+0]*a4.x + wA[j4*4+1]*a4.y
                             + wA[j4*4+2]*a4.z + wA[j4*4+3]*a4.w;
                    }
                    #pragma unroll
                    for (int j4 = 0; j4 < 13; ++j4) {
                        const float4 b4 = hpB[j4];
                        acc += wB[j4*4+0]*b4.x + wB[j4*4+1]*b4.y
                             + wB[j4*4+2]*b4.z + wB[j4*4+3]*b4.w;
                    }
                }
                gbuf[layer][g] = acc;
            }
        } else if (layer == 0 && g >= 204 && g < 208) {
            const int t = tau - 3;                  // output partials for h2(t)
            if (t >= 0) {
                const int k = g - 204;
                float p = 0.f;
                #pragma unroll
                for (int j = 0; j < 13; ++j) {
                    const int idx = k * 13 + j;
                    p += wl[j] * ((idx < 51) ? hbuf[2][idx] : 0.f);
                }
                opart[k] = p;
            }
        }
        __syncthreads();
        // ---------------- phase B: cell update ----------------
        if (gate_thread && g < HID) {
            const int t = tau - layer;
            if (t >= 0 && t < T) {
                const float gi = gbuf[layer][g];
                const float gf = gbuf[layer][HID + g];
                const float gg = gbuf[layer][2*HID + g];
                const float go = gbuf[layer][3*HID + g];
                const float si = 1.f / (1.f + expf(-gi));
                const float sf = 1.f / (1.f + expf(-gf));
                const float so = 1.f / (1.f + expf(-go));
                const float c  = sf * c_state + si * tanhf(gg);
                c_state = c;
                hbuf[layer][g] = so * tanhf(c);
            }
        } else if (layer == 0 && g == 208) {
            const int t = tau - 3;
            if (t >= 0) out[b * T + t] = opart[0] + opart[1] + opart[2] + opart[3] + blv;
        }
        __syncthreads();
    }
}

extern "C" void kernel_launch(void* const* d_in, const int* in_sizes, int n_in,
                              void* d_out, int out_size, void* d_ws, size_t ws_size,
                              hipStream_t stream) {
    const float* x    = (const float*)d_in[0];
    const float* Wih1 = (const float*)d_in[1];
    const float* Whh1 = (const float*)d_in[2];
    const float* bih1 = (const float*)d_in[3];
    const float* bhh1 = (const float*)d_in[4];
    const float* Wih  = (const float*)d_in[5];
    const float* Whh  = (const float*)d_in[6];
    const float* bih  = (const float*)d_in[7];
    const float* bhh  = (const float*)d_in[8];
    const float* Wl   = (const float*)d_in[9];
    const float* bl   = (const float*)d_in[10];
    float* out = (float*)d_out;

    const int T = in_sizes[0] / BATCH;   // 2048
    lstm3_kernel<<<BATCH, BLK, 0, stream>>>(x, Wih1, Whh1, bih1, bhh1,
                                            Wih, Whh, bih, bhh, Wl, bl, out, T);
}

// Round 3
// 2322.730 us; speedup vs baseline: 1.3354x; 1.3354x over previous
//
#include <hip/hip_runtime.h>
#include <cmath>

#define HID 51
#define NG  204      // 4*HID gates per cell
#define BATCH 256
#define BLK 1024     // 16 waves; max workgroup size on gfx950 (1280 was invalid!)

// One block per batch element. 1020 "row-dot" threads, uniform phase-A path:
//   tid    0..203 : layer0 gate g   = bias + wx*x[t]  + Whh1[g,:] . h0      (t = tau)
//   tid  204..407 : layer1 gate g  partial A = bias + Wih[0][g,:] . h0      (t = tau-1)
//   tid  408..611 : layer1 gate g  partial B =        Whh[0][g,:] . h1      (t = tau-1)
//   tid  612..815 : layer2 gate g  partial A = bias + Wih[1][g,:] . h1      (t = tau-2)
//   tid  816..1019: layer2 gate g  partial B =        Whh[1][g,:] . h2      (t = tau-2)
//   tid 1020      : output         = bl + Wl . h2                           (t = tau-3)
// Phase A: each thread one 52-length dot (weights in VGPRs) -> LDS slot.
// Phase B: 153 cell threads combine partials (c in register), h -> LDS;
//          tid 1020 stores the output slot to global.

__global__ __launch_bounds__(BLK, 4)
void lstm3_kernel(const float* __restrict__ x,
                  const float* __restrict__ Wih1, const float* __restrict__ Whh1,
                  const float* __restrict__ bih1, const float* __restrict__ bhh1,
                  const float* __restrict__ Wih,  const float* __restrict__ Whh,
                  const float* __restrict__ bih,  const float* __restrict__ bhh,
                  const float* __restrict__ Wl,   const float* __restrict__ bl,
                  float* __restrict__ out, int T)
{
    const int b   = blockIdx.x;
    const int tid = threadIdx.x;

    __shared__ __align__(16) float xbuf[2048];
    __shared__ __align__(16) float hbuf[3][52];   // hbuf[l][51] == 0 pad
    __shared__ __align__(16) float gP[6][NG];     // rows 0..4 = gate partials, row 5 = zeros
    __shared__ float oslot[2];                    // [0] = output dot, [1] = dummy sink

    // stage x row (read-once) into LDS
    for (int i = tid; i < T; i += BLK) xbuf[i] = x[(size_t)b * T + i];
    if (tid < 156) ((float*)hbuf)[tid] = 0.f;     // zero h state (+pads)
    if (tid < NG)  gP[5][tid] = 0.f;              // permanent zero row (layer0's s2)

    // ---------------- per-thread role setup (once) ----------------
    float w[52];
    #pragma unroll
    for (int j = 0; j < 52; ++j) w[j] = 0.f;
    float wx = 0.f, bias = 0.f;
    int t_off = 1 << 20;                // default: predicate never true
    const float* hsrc = hbuf[0];
    float* gdst = &oslot[1];

    if (tid < NG) {                                   // layer0 full row
        const int g = tid;
        wx   = Wih1[g];
        bias = bih1[g] + bhh1[g];
        for (int j = 0; j < 51; ++j) w[j] = Whh1[g * 51 + j];
        hsrc = hbuf[0]; gdst = &gP[0][g]; t_off = 0;
    } else if (tid < 2 * NG) {                        // layer1 A: Wih vs h0
        const int g = tid - NG;
        bias = bih[g] + bhh[g];
        const float* row = Wih + (size_t)g * 51;
        for (int j = 0; j < 51; ++j) w[j] = row[j];
        hsrc = hbuf[0]; gdst = &gP[1][g]; t_off = 1;
    } else if (tid < 3 * NG) {                        // layer1 B: Whh vs h1
        const int g = tid - 2 * NG;
        const float* row = Whh + (size_t)g * 51;
        for (int j = 0; j < 51; ++j) w[j] = row[j];
        hsrc = hbuf[1]; gdst = &gP[2][g]; t_off = 1;
    } else if (tid < 4 * NG) {                        // layer2 A: Wih vs h1
        const int g = tid - 3 * NG;
        bias = bih[NG + g] + bhh[NG + g];
        const float* row = Wih + (size_t)(NG + g) * 51;
        for (int j = 0; j < 51; ++j) w[j] = row[j];
        hsrc = hbuf[1]; gdst = &gP[3][g]; t_off = 2;
    } else if (tid < 5 * NG) {                        // layer2 B: Whh vs h2
        const int g = tid - 4 * NG;
        const float* row = Whh + (size_t)(NG + g) * 51;
        for (int j = 0; j < 51; ++j) w[j] = row[j];
        hsrc = hbuf[2]; gdst = &gP[4][g]; t_off = 2;
    } else if (tid == 1020) {                         // output dot: Wl vs h2
        bias = bl[0];
        for (int j = 0; j < 51; ++j) w[j] = Wl[j];
        hsrc = hbuf[2]; gdst = &oslot[0]; t_off = 3;
    }
    w[51] = 0.f;

    // phase-B role
    const bool is_cell = (tid < 3 * HID);             // 153 cell threads
    int cl = 0, cu = 0;
    const float *s1 = gP[0], *s2 = gP[5];
    if (is_cell) {
        cl = tid / HID;  cu = tid - cl * HID;
        if      (cl == 1) { s1 = gP[1]; s2 = gP[2]; }
        else if (cl == 2) { s1 = gP[3]; s2 = gP[4]; }
    }

    float c_state = 0.f;
    __syncthreads();

    const int TICKS = T + 3;
    for (int tau = 0; tau < TICKS; ++tau) {
        // ---------------- phase A: uniform row dots ----------------
        {
            const int t = tau - t_off;
            const bool pred = (unsigned)t < (unsigned)T;
            const int tx = pred ? t : 0;
            float acc0 = bias + wx * xbuf[tx];
            float acc1 = 0.f;
            const float4* hp = (const float4*)hsrc;
            #pragma unroll
            for (int j4 = 0; j4 < 13; ++j4) {
                const float4 h4 = hp[j4];
                const float s = w[4*j4+0]*h4.x + w[4*j4+1]*h4.y
                              + w[4*j4+2]*h4.z + w[4*j4+3]*h4.w;
                if (j4 & 1) acc1 += s; else acc0 += s;
            }
            if (pred) *gdst = acc0 + acc1;
        }
        __syncthreads();
        // ---------------- phase B: cell updates ----------------
        if (is_cell) {
            const int t = tau - cl;
            if ((unsigned)t < (unsigned)T) {
                const float gi = s1[cu]           + s2[cu];
                const float gf = s1[HID + cu]     + s2[HID + cu];
                const float gg = s1[2*HID + cu]   + s2[2*HID + cu];
                const float go = s1[3*HID + cu]   + s2[3*HID + cu];
                const float si = 1.f / (1.f + expf(-gi));
                const float sf = 1.f / (1.f + expf(-gf));
                const float so = 1.f / (1.f + expf(-go));
                const float c  = sf * c_state + si * tanhf(gg);
                c_state = c;
                hbuf[cl][cu] = so * tanhf(c);
            }
        } else if (tid == 1020) {
            const int t = tau - 3;
            if ((unsigned)t < (unsigned)T) out[(size_t)b * T + t] = oslot[0];
        }
        __syncthreads();
    }
}

extern "C" void kernel_launch(void* const* d_in, const int* in_sizes, int n_in,
                              void* d_out, int out_size, void* d_ws, size_t ws_size,
                              hipStream_t stream) {
    const float* x    = (const float*)d_in[0];
    const float* Wih1 = (const float*)d_in[1];
    const float* Whh1 = (const float*)d_in[2];
    const float* bih1 = (const float*)d_in[3];
    const float* bhh1 = (const float*)d_in[4];
    const float* Wih  = (const float*)d_in[5];
    const float* Whh  = (const float*)d_in[6];
    const float* bih  = (const float*)d_in[7];
    const float* bhh  = (const float*)d_in[8];
    const float* Wl   = (const float*)d_in[9];
    const float* bl   = (const float*)d_in[10];
    float* out = (float*)d_out;

    const int T = in_sizes[0] / BATCH;   // 2048
    lstm3_kernel<<<BATCH, BLK, 0, stream>>>(x, Wih1, Whh1, bih1, bhh1,
                                            Wih, Whh, bih, bhh, Wl, bl, out, T);
}